// Round 10
// baseline (253.001 us; speedup 1.0000x reference)
//
#include <hip/hip_runtime.h>
#include <stdint.h>

#define D_DIM 512

typedef __attribute__((ext_vector_type(8))) short bf16x8;
typedef __attribute__((ext_vector_type(4))) float f32x4;
typedef __attribute__((ext_vector_type(4))) short short4_t;
typedef __attribute__((ext_vector_type(4))) float float4_t;

__device__ __forceinline__ unsigned short f2bf(float f) {
  unsigned u = __float_as_uint(f);
  u += 0x7FFFu + ((u >> 16) & 1u);
  return (unsigned short)(u >> 16);
}

__device__ __forceinline__ float bf2f(unsigned short s) {
  return __uint_as_float(((unsigned)s) << 16);
}

__device__ __forceinline__ float tanh_fast(float x) {
  float e = __expf(2.0f * x);
  return 1.0f - 2.0f / (e + 1.0f);
}

__device__ __forceinline__ bf16x8 cvt8(float4_t a, float4_t b) {
  bf16x8 r;
  r[0] = (short)f2bf(a.x); r[1] = (short)f2bf(a.y);
  r[2] = (short)f2bf(a.z); r[3] = (short)f2bf(a.w);
  r[4] = (short)f2bf(b.x); r[5] = (short)f2bf(b.y);
  r[6] = (short)f2bf(b.z); r[7] = (short)f2bf(b.w);
  return r;
}

#define GLOAD_LDS16(gsrc, ldst) \
  __builtin_amdgcn_global_load_lds((const __attribute__((address_space(1))) void*)(gsrc), \
                                   (__attribute__((address_space(3))) void*)(ldst), 16, 0, 0)

// ---------------- small utility kernels ----------------

__global__ void cvt_f32_bf16_k(const float* __restrict__ in, unsigned short* __restrict__ out, int n4) {
  int i = blockIdx.x * blockDim.x + threadIdx.x;
  if (i < n4) {
    float4_t v = ((const float4_t*)in)[i];
    short4_t s;
    s.x = (short)f2bf(v.x); s.y = (short)f2bf(v.y);
    s.z = (short)f2bf(v.z); s.w = (short)f2bf(v.w);
    ((short4_t*)out)[i] = s;
  }
}

__global__ void cvt3_f32_bf16_k(const float* __restrict__ a, const float* __restrict__ b,
                                const float* __restrict__ c, unsigned short* __restrict__ out,
                                int n4each) {
  int i = blockIdx.x * blockDim.x + threadIdx.x;
  if (i >= 3 * n4each) return;
  int sel = i / n4each, j = i - sel * n4each;
  const float* src = (sel == 0) ? a : (sel == 1) ? b : c;
  float4_t v = ((const float4_t*)src)[j];
  short4_t s;
  s.x = (short)f2bf(v.x); s.y = (short)f2bf(v.y);
  s.z = (short)f2bf(v.z); s.w = (short)f2bf(v.w);
  ((short4_t*)out)[i] = s;
}

__global__ void prep_cluster_k(const int* __restrict__ vn, const int* __restrict__ nid,
                               int* __restrict__ cl, int* __restrict__ counts, int B) {
  int i = blockIdx.x * blockDim.x + threadIdx.x;
  if (i < B) {
    int c = vn[2 * nid[i] + 1];
    cl[i] = c;
    atomicAdd(&counts[c], 1);
  }
}

__global__ void prefix_k(const int* __restrict__ counts, int* __restrict__ starts,
                         int* __restrict__ cursor, int C) {
  __shared__ int sh[1024];
  int t = threadIdx.x;
  int v = (t < C) ? counts[t] : 0;
  sh[t] = v;
  __syncthreads();
  for (int off = 1; off < 1024; off <<= 1) {
    int x = (t >= off) ? sh[t - off] : 0;
    __syncthreads();
    sh[t] += x;
    __syncthreads();
  }
  if (t < C) { int st = sh[t] - v; starts[t] = st; cursor[t] = st; }
  if (t == 1023) starts[C] = sh[1023];
}

__global__ void scatter_k(const int* __restrict__ cl, int* __restrict__ cursor,
                          int* __restrict__ order, int B) {
  int i = blockIdx.x * blockDim.x + threadIdx.x;
  if (i < B) {
    int pos = atomicAdd(&cursor[cl[i]], 1);
    order[pos] = i;
  }
}

__device__ __forceinline__ unsigned enc_f(float f) {
  unsigned u = __float_as_uint(f);
  return (u & 0x80000000u) ? ~u : (u | 0x80000000u);
}
__device__ __forceinline__ float dec_f(unsigned u) {
  return __uint_as_float((u & 0x80000000u) ? (u & 0x7FFFFFFFu) : ~u);
}

__global__ void seg_max_k(const float* __restrict__ score, const int* __restrict__ cl,
                          unsigned* __restrict__ smax, int B) {
  int i = blockIdx.x * blockDim.x + threadIdx.x;
  if (i < B) atomicMax(&smax[cl[i]], enc_f(score[i]));
}

__global__ void seg_expsum_k(const float* __restrict__ score, const int* __restrict__ cl,
                             const unsigned* __restrict__ smax, float* __restrict__ ev,
                             float* __restrict__ denom, int B) {
  int i = blockIdx.x * blockDim.x + threadIdx.x;
  if (i < B) {
    int c = cl[i];
    float x = __expf(score[i] - dec_f(smax[c]));
    ev[i] = x;
    atomicAdd(&denom[c], x);
  }
}

__global__ __launch_bounds__(256)
void ctx_k(const unsigned short* __restrict__ hbf, const float* __restrict__ ev,
           const int* __restrict__ order, const int* __restrict__ starts,
           const float* __restrict__ denom, float* __restrict__ ctx) {
  int c = blockIdx.x;
  int t = threadIdx.x;
  int s0 = starts[c], s1 = starts[c + 1];
  float a0 = 0.f, a1 = 0.f;
  int j = s0;
  for (; j + 3 < s1; j += 4) {
    int i0 = order[j], i1 = order[j + 1], i2 = order[j + 2], i3 = order[j + 3];
    float e0 = ev[i0], e1 = ev[i1], e2 = ev[i2], e3 = ev[i3];
    unsigned u0 = *(const unsigned*)(hbf + (size_t)i0 * D_DIM + t * 2);
    unsigned u1 = *(const unsigned*)(hbf + (size_t)i1 * D_DIM + t * 2);
    unsigned u2 = *(const unsigned*)(hbf + (size_t)i2 * D_DIM + t * 2);
    unsigned u3 = *(const unsigned*)(hbf + (size_t)i3 * D_DIM + t * 2);
    a0 += e0 * bf2f((unsigned short)u0) + e1 * bf2f((unsigned short)u1)
        + e2 * bf2f((unsigned short)u2) + e3 * bf2f((unsigned short)u3);
    a1 += e0 * bf2f((unsigned short)(u0 >> 16)) + e1 * bf2f((unsigned short)(u1 >> 16))
        + e2 * bf2f((unsigned short)(u2 >> 16)) + e3 * bf2f((unsigned short)(u3 >> 16));
  }
  for (; j < s1; ++j) {
    int i0 = order[j];
    float e0 = ev[i0];
    unsigned u0 = *(const unsigned*)(hbf + (size_t)i0 * D_DIM + t * 2);
    a0 += e0 * bf2f((unsigned short)u0);
    a1 += e0 * bf2f((unsigned short)(u0 >> 16));
  }
  float inv = 1.0f / denom[c];
  float2 r = make_float2(a0 * inv, a1 * inv);
  *(float2*)(&ctx[(size_t)c * D_DIM + t * 2]) = r;
}

// ====== FUSED score GEMM: 128x128 tile, BK=32 dbuf, 256 thr, 3 blocks/CU ======
// A comes from h (f32): reg-load -> f2bf convert -> ds_write (T14 reg-staging,
// required since a transform is applied) -> also written back to hbf by the
// n0==0 sibling (each 128-row panel written exactly once; clamped tail rows
// write duplicate-identical values -> benign). This REPLACES the standalone
// 51us h->bf16 convert pass. B stays global_load_lds with pre-swizzled source.
// Structure = R5's proven 3-blocks/CU shape (best TLP: 142us) with R9's
// conflict-free swizzle slot^((row>>1)&3) and single barrier per K-step.
// __launch_bounds__(256,3) caps VGPR at 170 so 3 waves/SIMD residency holds.
// Epilogue: score[m] += sum_{128 cols} tanh(acc + qb[cl[m]][col])*Ws[col].
__global__ __launch_bounds__(256, 3)
void gemm128_fused_score_k(const float* __restrict__ h,
                           const unsigned short* __restrict__ Bw, int M,
                           const float* __restrict__ qb, const int* __restrict__ cl,
                           const float* __restrict__ Ws,
                           unsigned short* __restrict__ hbf,
                           float* __restrict__ out)
{
  __shared__ unsigned short As[2][128 * 32];
  __shared__ unsigned short Bs[2][128 * 32];
  __shared__ float red[128][2];
  __shared__ int clds[128];

  const int t = threadIdx.x;
  const int lane = t & 63;
  const int w = t >> 6;             // wave 0..3
  const int wr = w >> 1, wc = w & 1;
  const int l15 = lane & 15, l4 = lane >> 4;

  // m204 bijective XCD-chunk swizzle
  int id;
  {
    int nwg = gridDim.x;
    int q = nwg >> 3, r = nwg & 7;
    int xcd = blockIdx.x & 7, pos = blockIdx.x >> 3;
    id = (xcd < r ? xcd * (q + 1) : r * (q + 1) + (xcd - r) * q) + pos;
  }
  const int n0 = (id & 3) * 128;    // N fastest: 4 siblings share the A panel
  const int m0 = (id >> 2) * 128;
  const bool writer = (n0 == 0);

  if (t < 128) {
    int gm = m0 + t;
    clds[t] = cl[gm < M ? gm : M - 1];
  }

  // ---- A staging geometry (f32 reg path): 2 chunks/wave, chunk = 16 rows ----
  // lane: row-in-chunk = lane>>2, col group = (lane&3)*8 floats (2x float4)
  const int rin = lane >> 2;
  const int sl = lane & 3;

  const float* srcA[2];
  int dstA[2];
  unsigned short* hdst[2];
  #pragma unroll
  for (int c = 0; c < 2; ++c) {
    int chunk = w * 2 + c;
    int row = chunk * 16 + rin;                 // 0..127
    int ga = m0 + row; if (ga > M - 1) ga = M - 1;
    srcA[c] = h + (size_t)ga * 512 + sl * 8;
    dstA[c] = row * 64 + ((sl ^ ((row >> 1) & 3)) * 16);   // swizzled LDS byte off
    hdst[c] = hbf + (size_t)ga * 512 + sl * 8;
  }
  // ---- B staging via global_load_lds, source pre-swizzled ----
  const unsigned short* srcB[2];
  int dstB[2];
  #pragma unroll
  for (int c = 0; c < 2; ++c) {
    int chunk = w * 2 + c;
    int row = chunk * 16 + rin;
    int slot = sl ^ ((row >> 1) & 3);
    srcB[c] = Bw + (size_t)(n0 + row) * 512 + slot * 8;
    dstB[c] = chunk * 1024;
  }

  // fragment LDS byte offsets (loop-invariant)
  int offA[4], offB[4];
  #pragma unroll
  for (int mi = 0; mi < 4; ++mi) {
    int row = wr * 64 + mi * 16 + l15;
    offA[mi] = row * 64 + ((l4 ^ ((row >> 1) & 3)) * 16);
  }
  #pragma unroll
  for (int ni = 0; ni < 4; ++ni) {
    int row = wc * 64 + ni * 16 + l15;
    offB[ni] = row * 64 + ((l4 ^ ((row >> 1) & 3)) * 16);
  }

  f32x4 acc[4][4];
  #pragma unroll
  for (int mi = 0; mi < 4; ++mi)
    #pragma unroll
    for (int ni = 0; ni < 4; ++ni)
      acc[mi][ni] = (f32x4){0.f, 0.f, 0.f, 0.f};

  // ---- prologue: stage tile 0 (A via regs+convert, B via gload_lds) ----
  float4_t pa[2][2];
  #pragma unroll
  for (int c = 0; c < 2; ++c)
    GLOAD_LDS16(srcB[c], ((char*)Bs[0]) + dstB[c]);
  #pragma unroll
  for (int c = 0; c < 2; ++c) {
    pa[c][0] = *(const float4_t*)(srcA[c]);
    pa[c][1] = *(const float4_t*)(srcA[c] + 4);
  }
  __builtin_amdgcn_sched_barrier(0);
  asm volatile("s_waitcnt vmcnt(0)" ::: "memory");
  __builtin_amdgcn_sched_barrier(0);
  #pragma unroll
  for (int c = 0; c < 2; ++c) {
    bf16x8 v = cvt8(pa[c][0], pa[c][1]);
    *(bf16x8*)(((char*)As[0]) + dstA[c]) = v;
    if (writer) *(bf16x8*)(hdst[c]) = v;
  }
  asm volatile("s_waitcnt lgkmcnt(0)" ::: "memory");
  __builtin_amdgcn_sched_barrier(0);
  __builtin_amdgcn_s_barrier();     // tile 0 staged (also publishes clds)
  __builtin_amdgcn_sched_barrier(0);

  // ---- main loop: 16 K-steps, one barrier per step ----
  #pragma unroll
  for (int it = 0; it < 16; ++it) {
    const int cur = it & 1;
    // issue next tile's loads (B -> LDS buf^1, A -> regs)
    if (it < 15) {
      const int k1 = (it + 1) * 32;
      #pragma unroll
      for (int c = 0; c < 2; ++c)
        GLOAD_LDS16(srcB[c] + k1, ((char*)Bs[cur ^ 1]) + dstB[c]);
      #pragma unroll
      for (int c = 0; c < 2; ++c) {
        pa[c][0] = *(const float4_t*)(srcA[c] + k1);
        pa[c][1] = *(const float4_t*)(srcA[c] + k1 + 4);
      }
    }
    __builtin_amdgcn_sched_barrier(0);

    // compute tile it from buf cur
    {
      bf16x8 af[4], bfv[4];
      #pragma unroll
      for (int mi = 0; mi < 4; ++mi)
        af[mi] = *(const bf16x8*)(((const char*)As[cur]) + offA[mi]);
      #pragma unroll
      for (int ni = 0; ni < 4; ++ni)
        bfv[ni] = *(const bf16x8*)(((const char*)Bs[cur]) + offB[ni]);
      __builtin_amdgcn_s_setprio(1);
      #pragma unroll
      for (int mi = 0; mi < 4; ++mi)
        #pragma unroll
        for (int ni = 0; ni < 4; ++ni)
          acc[mi][ni] = __builtin_amdgcn_mfma_f32_16x16x32_bf16(af[mi], bfv[ni], acc[mi][ni], 0, 0, 0);
      __builtin_amdgcn_s_setprio(0);
    }
    __builtin_amdgcn_sched_barrier(0);

    // land next tile: wait A-regs (+B), convert + ds_write (+hbf writeback)
    if (it < 15) {
      asm volatile("s_waitcnt vmcnt(0)" ::: "memory");
      __builtin_amdgcn_sched_barrier(0);
      const int k1 = (it + 1) * 32;
      #pragma unroll
      for (int c = 0; c < 2; ++c) {
        bf16x8 v = cvt8(pa[c][0], pa[c][1]);
        *(bf16x8*)(((char*)As[cur ^ 1]) + dstA[c]) = v;
        if (writer) *(bf16x8*)(hdst[c] + k1) = v;
      }
      asm volatile("s_waitcnt lgkmcnt(0)" ::: "memory");
    }
    __builtin_amdgcn_sched_barrier(0);
    __builtin_amdgcn_s_barrier();   // publishes tile it+1; frees nothing early
    __builtin_amdgcn_sched_barrier(0);
  }

  // ---- epilogue: fused additive-attention partial score over 128 cols ----
  #pragma unroll
  for (int mi = 0; mi < 4; ++mi) {
    #pragma unroll
    for (int r = 0; r < 4; ++r) {
      int rowt = wr * 64 + mi * 16 + l4 * 4 + r;
      int c = clds[rowt];
      const float* qrow = &qb[(size_t)c * 512];
      float s = 0.f;
      #pragma unroll
      for (int ni = 0; ni < 4; ++ni) {
        int gcol = n0 + wc * 64 + ni * 16 + l15;
        float x = acc[mi][ni][r] + qrow[gcol];
        s += tanh_fast(x) * Ws[gcol];
      }
      s += __shfl_xor(s, 1);
      s += __shfl_xor(s, 2);
      s += __shfl_xor(s, 4);
      s += __shfl_xor(s, 8);
      if (l15 == 0) red[rowt][wc] = s;
    }
  }
  __syncthreads();
  if (t < 128) {
    int gm = m0 + t;
    if (gm < M) atomicAdd(&out[gm], red[t][0] + red[t][1]);
  }
}

// --- bf16 MFMA GEMM: 128x128 tile, BK=32 (R9 version) -- small GEMMs only ---
template<int EPI>
__global__ __launch_bounds__(256)
void gemm128_k(const unsigned short* __restrict__ Abf,
               const unsigned short* __restrict__ Bw, int M,
               const float* __restrict__ bias, float* __restrict__ out)
{
  __shared__ unsigned short As[2][128 * 32];
  __shared__ unsigned short Bs[2][128 * 32];

  const int t = threadIdx.x;
  const int lane = t & 63;
  const int w = t >> 6;
  const int wr = w >> 1, wc = w & 1;
  const int l15 = lane & 15, l4 = lane >> 4;

  const int nwg = gridDim.x;
  int id = blockIdx.x;
  if ((nwg & 7) == 0) id = (id & 7) * (nwg >> 3) + (id >> 3);
  const int n0 = (id & 3) * 128;
  const int m0 = (id >> 2) * 128;

  const int rin = lane >> 2;
  const int sl = lane & 3;

  const unsigned short* srcA[2];
  const unsigned short* srcB[2];
  int dstOff[2];
  #pragma unroll
  for (int c = 0; c < 2; ++c) {
    int chunk = w * 2 + c;
    int row = chunk * 16 + rin;
    int slot = sl ^ ((row >> 1) & 3);
    int ga = m0 + row; if (ga > M - 1) ga = M - 1;
    srcA[c] = Abf + (size_t)ga * 512 + slot * 8;
    srcB[c] = Bw + (size_t)(n0 + row) * 512 + slot * 8;
    dstOff[c] = chunk * 1024;
  }

  int offA[4], offB[4];
  #pragma unroll
  for (int mi = 0; mi < 4; ++mi) {
    int row = wr * 64 + mi * 16 + l15;
    offA[mi] = row * 64 + ((l4 ^ ((row >> 1) & 3)) * 16);
  }
  #pragma unroll
  for (int ni = 0; ni < 4; ++ni) {
    int row = wc * 64 + ni * 16 + l15;
    offB[ni] = row * 64 + ((l4 ^ ((row >> 1) & 3)) * 16);
  }

  f32x4 acc[4][4];
  #pragma unroll
  for (int mi = 0; mi < 4; ++mi)
    #pragma unroll
    for (int ni = 0; ni < 4; ++ni)
      acc[mi][ni] = (f32x4){0.f, 0.f, 0.f, 0.f};

  #pragma unroll
  for (int c = 0; c < 2; ++c) {
    GLOAD_LDS16(srcA[c], ((char*)As[0]) + dstOff[c]);
    GLOAD_LDS16(srcB[c], ((char*)Bs[0]) + dstOff[c]);
  }
  __builtin_amdgcn_sched_barrier(0);

  #pragma unroll
  for (int it = 0; it < 16; ++it) {
    const int cur = it & 1;
    asm volatile("s_waitcnt vmcnt(0)" ::: "memory");
    __builtin_amdgcn_sched_barrier(0);
    __builtin_amdgcn_s_barrier();
    __builtin_amdgcn_sched_barrier(0);
    if (it < 15) {
      const int k1 = (it + 1) * 32;
      #pragma unroll
      for (int c = 0; c < 2; ++c) {
        GLOAD_LDS16(srcA[c] + k1, ((char*)As[cur ^ 1]) + dstOff[c]);
        GLOAD_LDS16(srcB[c] + k1, ((char*)Bs[cur ^ 1]) + dstOff[c]);
      }
    }
    {
      bf16x8 af[4], bfv[4];
      #pragma unroll
      for (int mi = 0; mi < 4; ++mi)
        af[mi] = *(const bf16x8*)(((const char*)As[cur]) + offA[mi]);
      #pragma unroll
      for (int ni = 0; ni < 4; ++ni)
        bfv[ni] = *(const bf16x8*)(((const char*)Bs[cur]) + offB[ni]);
      #pragma unroll
      for (int mi = 0; mi < 4; ++mi)
        #pragma unroll
        for (int ni = 0; ni < 4; ++ni)
          acc[mi][ni] = __builtin_amdgcn_mfma_f32_16x16x32_bf16(af[mi], bfv[ni], acc[mi][ni], 0, 0, 0);
    }
    __builtin_amdgcn_sched_barrier(0);
  }

  #pragma unroll
  for (int mi = 0; mi < 4; ++mi) {
    #pragma unroll
    for (int r = 0; r < 4; ++r) {
      int gm = m0 + wr * 64 + mi * 16 + l4 * 4 + r;
      if (gm < M) {
        #pragma unroll
        for (int ni = 0; ni < 4; ++ni) {
          int gcol = n0 + wc * 64 + ni * 16 + l15;
          float v = acc[mi][ni][r] + bias[gcol];
          if (EPI == 2) v = tanh_fast(v);
          out[(size_t)gm * 512 + gcol] = v;
        }
      }
    }
  }
}

// ---------------- host side ----------------

extern "C" void kernel_launch(void* const* d_in, const int* in_sizes, int n_in,
                              void* d_out, int out_size, void* d_ws, size_t ws_size,
                              hipStream_t stream) {
  const float* h  = (const float*)d_in[0];
  const float* g  = (const float*)d_in[1];
  const int*   vn = (const int*)d_in[2];
  const int*   nid= (const int*)d_in[3];
  const float* Wq = (const float*)d_in[4];
  const float* Wk = (const float*)d_in[5];
  const float* ab = (const float*)d_in[6];
  const float* Ws = (const float*)d_in[7];
  const float* W  = (const float*)d_in[9];
  const float* b  = (const float*)d_in[10];

  const int B = in_sizes[3];          // 100000
  const int C = in_sizes[1] / D_DIM;  // 1000

  char* wsb = (char*)d_ws;
  size_t off = 0;
  auto alloc = [&](size_t bytes) -> void* {
    void* p = wsb + off;
    off += (bytes + 255) & ~(size_t)255;
    return p;
  };

  unsigned short* hbf   = (unsigned short*)alloc((size_t)B * 512 * 2);
  unsigned short* gbf   = (unsigned short*)alloc((size_t)C * 512 * 2);
  unsigned short* ctxbf = (unsigned short*)alloc((size_t)C * 512 * 2);
  unsigned short* Wk_bf = (unsigned short*)alloc((size_t)512 * 512 * 2);  // contiguous
  unsigned short* Wq_bf = (unsigned short*)alloc((size_t)512 * 512 * 2);  // with Wk_bf
  unsigned short* W_bf  = (unsigned short*)alloc((size_t)512 * 512 * 2);  // and Wq_bf
  float* qb    = (float*)alloc((size_t)C * 512 * 4);
  float* ctx   = (float*)alloc((size_t)C * 512 * 4);
  float* score = (float*)alloc((size_t)B * 4);
  float* ev    = (float*)alloc((size_t)B * 4);
  int*   cl    = (int*)alloc((size_t)B * 4);
  int*   order = (int*)alloc((size_t)B * 4);
  int*      counts = (int*)alloc((size_t)C * 4);
  unsigned* smax   = (unsigned*)alloc((size_t)C * 4);
  float*    denom  = (float*)alloc((size_t)C * 4);
  int* starts = (int*)alloc((size_t)(C + 1) * 4);
  int* cursor = (int*)alloc((size_t)C * 4);
  (void)ws_size; (void)n_in; (void)out_size;

  size_t zlen = (size_t)((char*)denom - (char*)counts) + (size_t)C * 4;
  hipMemsetAsync(counts, 0, zlen, stream);
  hipMemsetAsync(score, 0, (size_t)B * 4, stream);

  // small conversions (g, weights); h is converted INSIDE the fused score GEMM
  cvt_f32_bf16_k<<<(C * 512 / 4 + 255) / 256, 256, 0, stream>>>(g, gbf, C * 512 / 4);
  const int n4w = 512 * 512 / 4;
  cvt3_f32_bf16_k<<<(3 * n4w + 255) / 256, 256, 0, stream>>>(Wk, Wq, W, Wk_bf, n4w);

  prep_cluster_k<<<(B + 255) / 256, 256, 0, stream>>>(vn, nid, cl, counts, B);
  prefix_k<<<1, 1024, 0, stream>>>(counts, starts, cursor, C);
  scatter_k<<<(B + 255) / 256, 256, 0, stream>>>(cl, cursor, order, B);

  // qb = g @ Wq^T + attn_bias
  gemm128_k<0><<<4 * ((C + 127) / 128), 256, 0, stream>>>(gbf, Wq_bf, C, ab, qb);

  // score[m] += per-128-col-block sum of tanh(h@Wk^T + qb[cl])·Ws
  // (bs dropped: softmax invariant to constant shift). Also converts h -> hbf.
  gemm128_fused_score_k<<<4 * ((B + 127) / 128), 256, 0, stream>>>(
      h, Wk_bf, B, qb, cl, Ws, hbf, score);

  seg_max_k<<<(B + 255) / 256, 256, 0, stream>>>(score, cl, smax, B);
  seg_expsum_k<<<(B + 255) / 256, 256, 0, stream>>>(score, cl, smax, ev, denom, B);
  ctx_k<<<C, 256, 0, stream>>>(hbf, ev, order, starts, denom, ctx);

  cvt_f32_bf16_k<<<(C * 512 / 4 + 255) / 256, 256, 0, stream>>>(ctx, ctxbf, C * 512 / 4);

  // out = tanh(ctx @ W^T + b)
  gemm128_k<2><<<4 * ((C + 127) / 128), 256, 0, stream>>>(ctxbf, W_bf, C, b, (float*)d_out);
}

// Round 11
// 235.772 us; speedup vs baseline: 1.0731x; 1.0731x over previous
//
#include <hip/hip_runtime.h>
#include <stdint.h>

#define D_DIM 512

typedef __attribute__((ext_vector_type(8))) short bf16x8;
typedef __attribute__((ext_vector_type(4))) float f32x4;
typedef __attribute__((ext_vector_type(4))) short short4_t;
typedef __attribute__((ext_vector_type(4))) float float4_t;

__device__ __forceinline__ unsigned short f2bf(float f) {
  unsigned u = __float_as_uint(f);
  u += 0x7FFFu + ((u >> 16) & 1u);
  return (unsigned short)(u >> 16);
}

__device__ __forceinline__ float bf2f(unsigned short s) {
  return __uint_as_float(((unsigned)s) << 16);
}

__device__ __forceinline__ float tanh_fast(float x) {
  float e = __expf(2.0f * x);
  return 1.0f - 2.0f / (e + 1.0f);
}

#define GLOAD_LDS16(gsrc, ldst) \
  __builtin_amdgcn_global_load_lds((const __attribute__((address_space(1))) void*)(gsrc), \
                                   (__attribute__((address_space(3))) void*)(ldst), 16, 0, 0)

// ---------------- small utility kernels ----------------

__global__ void cvt_f32_bf16_k(const float* __restrict__ in, unsigned short* __restrict__ out, int n4) {
  int i = blockIdx.x * blockDim.x + threadIdx.x;
  if (i < n4) {
    float4_t v = ((const float4_t*)in)[i];
    short4_t s;
    s.x = (short)f2bf(v.x); s.y = (short)f2bf(v.y);
    s.z = (short)f2bf(v.z); s.w = (short)f2bf(v.w);
    ((short4_t*)out)[i] = s;
  }
}

__global__ void cvt3_f32_bf16_k(const float* __restrict__ a, const float* __restrict__ b,
                                const float* __restrict__ c, unsigned short* __restrict__ out,
                                int n4each) {
  int i = blockIdx.x * blockDim.x + threadIdx.x;
  if (i >= 3 * n4each) return;
  int sel = i / n4each, j = i - sel * n4each;
  const float* src = (sel == 0) ? a : (sel == 1) ? b : c;
  float4_t v = ((const float4_t*)src)[j];
  short4_t s;
  s.x = (short)f2bf(v.x); s.y = (short)f2bf(v.y);
  s.z = (short)f2bf(v.z); s.w = (short)f2bf(v.w);
  ((short4_t*)out)[i] = s;
}

__global__ void prep_cluster_k(const int* __restrict__ vn, const int* __restrict__ nid,
                               int* __restrict__ cl, int* __restrict__ counts, int B) {
  int i = blockIdx.x * blockDim.x + threadIdx.x;
  if (i < B) {
    int c = vn[2 * nid[i] + 1];
    cl[i] = c;
    atomicAdd(&counts[c], 1);
  }
}

__global__ void prefix_k(const int* __restrict__ counts, int* __restrict__ starts,
                         int* __restrict__ cursor, int C) {
  __shared__ int sh[1024];
  int t = threadIdx.x;
  int v = (t < C) ? counts[t] : 0;
  sh[t] = v;
  __syncthreads();
  for (int off = 1; off < 1024; off <<= 1) {
    int x = (t >= off) ? sh[t - off] : 0;
    __syncthreads();
    sh[t] += x;
    __syncthreads();
  }
  if (t < C) { int st = sh[t] - v; starts[t] = st; cursor[t] = st; }
  if (t == 1023) starts[C] = sh[1023];
}

__global__ void scatter_k(const int* __restrict__ cl, int* __restrict__ cursor,
                          int* __restrict__ order, int B) {
  int i = blockIdx.x * blockDim.x + threadIdx.x;
  if (i < B) {
    int pos = atomicAdd(&cursor[cl[i]], 1);
    order[pos] = i;
  }
}

__device__ __forceinline__ unsigned enc_f(float f) {
  unsigned u = __float_as_uint(f);
  return (u & 0x80000000u) ? ~u : (u | 0x80000000u);
}
__device__ __forceinline__ float dec_f(unsigned u) {
  return __uint_as_float((u & 0x80000000u) ? (u & 0x7FFFFFFFu) : ~u);
}

__global__ void seg_max_k(const float* __restrict__ score, const int* __restrict__ cl,
                          unsigned* __restrict__ smax, int B) {
  int i = blockIdx.x * blockDim.x + threadIdx.x;
  if (i < B) atomicMax(&smax[cl[i]], enc_f(score[i]));
}

__global__ void seg_expsum_k(const float* __restrict__ score, const int* __restrict__ cl,
                             const unsigned* __restrict__ smax, float* __restrict__ ev,
                             float* __restrict__ denom, int B) {
  int i = blockIdx.x * blockDim.x + threadIdx.x;
  if (i < B) {
    int c = cl[i];
    float x = __expf(score[i] - dec_f(smax[c]));
    ev[i] = x;
    atomicAdd(&denom[c], x);
  }
}

__global__ __launch_bounds__(256)
void ctx_k(const unsigned short* __restrict__ hbf, const float* __restrict__ ev,
           const int* __restrict__ order, const int* __restrict__ starts,
           const float* __restrict__ denom, float* __restrict__ ctx) {
  int c = blockIdx.x;
  int t = threadIdx.x;
  int s0 = starts[c], s1 = starts[c + 1];
  float a0 = 0.f, a1 = 0.f;
  int j = s0;
  for (; j + 3 < s1; j += 4) {
    int i0 = order[j], i1 = order[j + 1], i2 = order[j + 2], i3 = order[j + 3];
    float e0 = ev[i0], e1 = ev[i1], e2 = ev[i2], e3 = ev[i3];
    unsigned u0 = *(const unsigned*)(hbf + (size_t)i0 * D_DIM + t * 2);
    unsigned u1 = *(const unsigned*)(hbf + (size_t)i1 * D_DIM + t * 2);
    unsigned u2 = *(const unsigned*)(hbf + (size_t)i2 * D_DIM + t * 2);
    unsigned u3 = *(const unsigned*)(hbf + (size_t)i3 * D_DIM + t * 2);
    a0 += e0 * bf2f((unsigned short)u0) + e1 * bf2f((unsigned short)u1)
        + e2 * bf2f((unsigned short)u2) + e3 * bf2f((unsigned short)u3);
    a1 += e0 * bf2f((unsigned short)(u0 >> 16)) + e1 * bf2f((unsigned short)(u1 >> 16))
        + e2 * bf2f((unsigned short)(u2 >> 16)) + e3 * bf2f((unsigned short)(u3 >> 16));
  }
  for (; j < s1; ++j) {
    int i0 = order[j];
    float e0 = ev[i0];
    unsigned u0 = *(const unsigned*)(hbf + (size_t)i0 * D_DIM + t * 2);
    a0 += e0 * bf2f((unsigned short)u0);
    a1 += e0 * bf2f((unsigned short)(u0 >> 16));
  }
  float inv = 1.0f / denom[c];
  float2 r = make_float2(a0 * inv, a1 * inv);
  *(float2*)(&ctx[(size_t)c * D_DIM + t * 2]) = r;
}

// ====== 256x256 score GEMM, BK=32, TRIPLE-buffered depth-2 prefetch ======
// R9 structure (best: 134us) with one change: prefetch DEPTH 2. R9 issued tile
// t+1's loads one body (~1500cy) before awaiting them with vmcnt(0) -- under
// the ~4200cy completion time (latency 900 + 32KB/CU transfer ~3300), so every
// step stalled ~2700cy (wall 6576 vs demand 3277). Now: body t issues tile t+2,
// top-of-body waits vmcnt(2) -- drains tile t (issued 2 bodies = ~2 walls ago),
// keeps t+1's 2 loads/wave IN FLIGHT (T4: never vmcnt(0) mid-loop). LDS 3x32KB
// buffers (static kt%3 via full unroll) + red/clds = ~101KB -> still 1 block/CU.
// 16 waves of 64x64; VGPR 64 + AGPR 64 = 128 -> exactly 4 waves/SIMD. Swizzle
// slot^((row>>1)&3) (R9: 0 conflicts); gload_lds linear dest + pre-swizzled src.
// Buffer-overwrite race check: tile t+2 targets buf (t-1)%3; every wave's
// body-(t-1) ds_reads were consumed by its MFMAs before it reached body t's
// barrier, and issues happen after that barrier -> safe.
__global__ __launch_bounds__(1024)
void gemm256sq_score_k(const unsigned short* __restrict__ Abf,
                       const unsigned short* __restrict__ Bw, int M,
                       const float* __restrict__ qb, const int* __restrict__ cl,
                       const float* __restrict__ Ws, float* __restrict__ out)
{
  // AB[buf]: A = elements [0, 8192) (256 rows x 32), B = [8192, 16384)
  __shared__ unsigned short AB[3][16384];
  __shared__ float red[256][4];
  __shared__ int clds[256];

  const int t = threadIdx.x;
  const int lane = t & 63;
  const int w = t >> 6;                 // 0..15
  const int wr = w >> 2, wc = w & 3;    // wave tile: rows wr*64, cols wc*64
  const int l15 = lane & 15, l4 = lane >> 4;

  // m204 bijective XCD-chunk swizzle
  int id;
  {
    int nwg = gridDim.x;
    int q = nwg >> 3, r = nwg & 7;
    int xcd = blockIdx.x & 7, pos = blockIdx.x >> 3;
    id = (xcd < r ? xcd * (q + 1) : r * (q + 1) + (xcd - r) * q) + pos;
  }
  const int n0 = (id & 1) * 256;        // N fastest: 2 siblings share A panel
  const int m0 = (id >> 1) * 256;

  // ---- staging: wave w stages A-chunk w and B-chunk w (1KB = 16 rows x 64B) ----
  const int rin = lane >> 2;
  const int lrow = w * 16 + rin;                    // row within tile 0..255
  const int sslot = (lane & 3) ^ ((lrow >> 1) & 3);
  int rowA = m0 + lrow; if (rowA > M - 1) rowA = M - 1;
  const unsigned short* srcA = Abf + (size_t)rowA * 512 + sslot * 8;
  const unsigned short* srcB = Bw + (size_t)(n0 + lrow) * 512 + sslot * 8;

  // fragment LDS byte offsets within one 32KB buffer
  int offA[4], offB[4];
  #pragma unroll
  for (int mi = 0; mi < 4; ++mi) {
    int row = wr * 64 + mi * 16 + l15;
    offA[mi] = row * 64 + ((l4 ^ ((row >> 1) & 3)) * 16);
  }
  #pragma unroll
  for (int ni = 0; ni < 4; ++ni) {
    int row = wc * 64 + ni * 16 + l15;
    offB[ni] = 16384 + row * 64 + ((l4 ^ ((row >> 1) & 3)) * 16);
  }

  f32x4 acc[4][4];
  #pragma unroll
  for (int mi = 0; mi < 4; ++mi)
    #pragma unroll
    for (int ni = 0; ni < 4; ++ni)
      acc[mi][ni] = (f32x4){0.f, 0.f, 0.f, 0.f};

  // prologue: issue tiles 0 and 1 into buffers 0 and 1
  GLOAD_LDS16(srcA, ((char*)&AB[0][0]) + w * 1024);
  GLOAD_LDS16(srcB, ((char*)&AB[0][8192]) + w * 1024);
  GLOAD_LDS16(srcA + 32, ((char*)&AB[1][0]) + w * 1024);
  GLOAD_LDS16(srcB + 32, ((char*)&AB[1][8192]) + w * 1024);
  __builtin_amdgcn_sched_barrier(0);

  #pragma unroll
  for (int kt = 0; kt < 16; ++kt) {
    const int b = kt % 3;
    // counted drain: tile kt's loads (issued 2 bodies ago) land; kt+1 stays in flight
    if (kt < 15) {
      asm volatile("s_waitcnt vmcnt(2)" ::: "memory");
    } else {
      asm volatile("s_waitcnt vmcnt(0)" ::: "memory");
    }
    __builtin_amdgcn_sched_barrier(0);
    __builtin_amdgcn_s_barrier();
    __builtin_amdgcn_sched_barrier(0);

    // issue tile kt+2 into buf (kt+2)%3 (compile-time constant after unroll)
    if (kt < 14) {
      const int k2 = (kt + 2) * 32;     // +64B per step
      GLOAD_LDS16(srcA + k2, ((char*)&AB[(kt + 2) % 3][0]) + w * 1024);
      GLOAD_LDS16(srcB + k2, ((char*)&AB[(kt + 2) % 3][8192]) + w * 1024);
    }

    bf16x8 a[4], bv[4];
    #pragma unroll
    for (int mi = 0; mi < 4; ++mi)
      a[mi] = *(const bf16x8*)(((const char*)AB[b]) + offA[mi]);
    #pragma unroll
    for (int ni = 0; ni < 4; ++ni)
      bv[ni] = *(const bf16x8*)(((const char*)AB[b]) + offB[ni]);
    __builtin_amdgcn_s_setprio(1);
    #pragma unroll
    for (int mi = 0; mi < 4; ++mi)
      #pragma unroll
      for (int ni = 0; ni < 4; ++ni)
        acc[mi][ni] = __builtin_amdgcn_mfma_f32_16x16x32_bf16(a[mi], bv[ni], acc[mi][ni], 0, 0, 0);
    __builtin_amdgcn_s_setprio(0);
    __builtin_amdgcn_sched_barrier(0);
  }

  // ---- epilogue: fused additive-attention partial score over 256 cols ----
  if (t < 256) {
    int gm = m0 + t;
    clds[t] = cl[gm < M ? gm : M - 1];
  }
  __syncthreads();
  #pragma unroll
  for (int mi = 0; mi < 4; ++mi) {
    #pragma unroll
    for (int r = 0; r < 4; ++r) {
      int rowt = wr * 64 + mi * 16 + l4 * 4 + r;
      int c = clds[rowt];
      const float* qrow = &qb[(size_t)c * 512];
      float s = 0.f;
      #pragma unroll
      for (int ni = 0; ni < 4; ++ni) {
        int gcol = n0 + wc * 64 + ni * 16 + l15;
        float x = acc[mi][ni][r] + qrow[gcol];
        s += tanh_fast(x) * Ws[gcol];
      }
      s += __shfl_xor(s, 1);
      s += __shfl_xor(s, 2);
      s += __shfl_xor(s, 4);
      s += __shfl_xor(s, 8);
      if (l15 == 0) red[rowt][wc] = s;
    }
  }
  __syncthreads();
  if (t < 256) {
    int gm = m0 + t;
    if (gm < M) atomicAdd(&out[gm], red[t][0] + red[t][1] + red[t][2] + red[t][3]);
  }
}

// --- bf16 MFMA GEMM: 128x128 tile, BK=32 (R9) -- small GEMMs only ---
template<int EPI>
__global__ __launch_bounds__(256)
void gemm128_k(const unsigned short* __restrict__ Abf,
               const unsigned short* __restrict__ Bw, int M,
               const float* __restrict__ bias, float* __restrict__ out)
{
  __shared__ unsigned short As[2][128 * 32];
  __shared__ unsigned short Bs[2][128 * 32];

  const int t = threadIdx.x;
  const int lane = t & 63;
  const int w = t >> 6;
  const int wr = w >> 1, wc = w & 1;
  const int l15 = lane & 15, l4 = lane >> 4;

  const int nwg = gridDim.x;
  int id = blockIdx.x;
  if ((nwg & 7) == 0) id = (id & 7) * (nwg >> 3) + (id >> 3);
  const int n0 = (id & 3) * 128;
  const int m0 = (id >> 2) * 128;

  const int rin = lane >> 2;
  const int sl = lane & 3;

  const unsigned short* srcA[2];
  const unsigned short* srcB[2];
  int dstOff[2];
  #pragma unroll
  for (int c = 0; c < 2; ++c) {
    int chunk = w * 2 + c;
    int row = chunk * 16 + rin;
    int slot = sl ^ ((row >> 1) & 3);
    int ga = m0 + row; if (ga > M - 1) ga = M - 1;
    srcA[c] = Abf + (size_t)ga * 512 + slot * 8;
    srcB[c] = Bw + (size_t)(n0 + row) * 512 + slot * 8;
    dstOff[c] = chunk * 1024;
  }

  int offA[4], offB[4];
  #pragma unroll
  for (int mi = 0; mi < 4; ++mi) {
    int row = wr * 64 + mi * 16 + l15;
    offA[mi] = row * 64 + ((l4 ^ ((row >> 1) & 3)) * 16);
  }
  #pragma unroll
  for (int ni = 0; ni < 4; ++ni) {
    int row = wc * 64 + ni * 16 + l15;
    offB[ni] = row * 64 + ((l4 ^ ((row >> 1) & 3)) * 16);
  }

  f32x4 acc[4][4];
  #pragma unroll
  for (int mi = 0; mi < 4; ++mi)
    #pragma unroll
    for (int ni = 0; ni < 4; ++ni)
      acc[mi][ni] = (f32x4){0.f, 0.f, 0.f, 0.f};

  #pragma unroll
  for (int c = 0; c < 2; ++c) {
    GLOAD_LDS16(srcA[c], ((char*)As[0]) + dstOff[c]);
    GLOAD_LDS16(srcB[c], ((char*)Bs[0]) + dstOff[c]);
  }
  __builtin_amdgcn_sched_barrier(0);

  #pragma unroll
  for (int it = 0; it < 16; ++it) {
    const int cur = it & 1;
    asm volatile("s_waitcnt vmcnt(0)" ::: "memory");
    __builtin_amdgcn_sched_barrier(0);
    __builtin_amdgcn_s_barrier();
    __builtin_amdgcn_sched_barrier(0);
    if (it < 15) {
      const int k1 = (it + 1) * 32;
      #pragma unroll
      for (int c = 0; c < 2; ++c) {
        GLOAD_LDS16(srcA[c] + k1, ((char*)As[cur ^ 1]) + dstOff[c]);
        GLOAD_LDS16(srcB[c] + k1, ((char*)Bs[cur ^ 1]) + dstOff[c]);
      }
    }
    {
      bf16x8 af[4], bfv[4];
      #pragma unroll
      for (int mi = 0; mi < 4; ++mi)
        af[mi] = *(const bf16x8*)(((const char*)As[cur]) + offA[mi]);
      #pragma unroll
      for (int ni = 0; ni < 4; ++ni)
        bfv[ni] = *(const bf16x8*)(((const char*)Bs[cur]) + offB[ni]);
      #pragma unroll
      for (int mi = 0; mi < 4; ++mi)
        #pragma unroll
        for (int ni = 0; ni < 4; ++ni)
          acc[mi][ni] = __builtin_amdgcn_mfma_f32_16x16x32_bf16(af[mi], bfv[ni], acc[mi][ni], 0, 0, 0);
    }
    __builtin_amdgcn_sched_barrier(0);
  }

  #pragma unroll
  for (int mi = 0; mi < 4; ++mi) {
    #pragma unroll
    for (int r = 0; r < 4; ++r) {
      int gm = m0 + wr * 64 + mi * 16 + l4 * 4 + r;
      if (gm < M) {
        #pragma unroll
        for (int ni = 0; ni < 4; ++ni) {
          int gcol = n0 + wc * 64 + ni * 16 + l15;
          float v = acc[mi][ni][r] + bias[gcol];
          if (EPI == 2) v = tanh_fast(v);
          out[(size_t)gm * 512 + gcol] = v;
        }
      }
    }
  }
}

// ---------------- host side ----------------

extern "C" void kernel_launch(void* const* d_in, const int* in_sizes, int n_in,
                              void* d_out, int out_size, void* d_ws, size_t ws_size,
                              hipStream_t stream) {
  const float* h  = (const float*)d_in[0];
  const float* g  = (const float*)d_in[1];
  const int*   vn = (const int*)d_in[2];
  const int*   nid= (const int*)d_in[3];
  const float* Wq = (const float*)d_in[4];
  const float* Wk = (const float*)d_in[5];
  const float* ab = (const float*)d_in[6];
  const float* Ws = (const float*)d_in[7];
  const float* W  = (const float*)d_in[9];
  const float* b  = (const float*)d_in[10];

  const int B = in_sizes[3];          // 100000
  const int C = in_sizes[1] / D_DIM;  // 1000

  char* wsb = (char*)d_ws;
  size_t off = 0;
  auto alloc = [&](size_t bytes) -> void* {
    void* p = wsb + off;
    off += (bytes + 255) & ~(size_t)255;
    return p;
  };

  unsigned short* hbf   = (unsigned short*)alloc((size_t)B * 512 * 2);
  unsigned short* gbf   = (unsigned short*)alloc((size_t)C * 512 * 2);
  unsigned short* ctxbf = (unsigned short*)alloc((size_t)C * 512 * 2);
  unsigned short* Wk_bf = (unsigned short*)alloc((size_t)512 * 512 * 2);  // contiguous
  unsigned short* Wq_bf = (unsigned short*)alloc((size_t)512 * 512 * 2);  // with Wk_bf
  unsigned short* W_bf  = (unsigned short*)alloc((size_t)512 * 512 * 2);  // and Wq_bf
  float* qb    = (float*)alloc((size_t)C * 512 * 4);
  float* ctx   = (float*)alloc((size_t)C * 512 * 4);
  float* score = (float*)alloc((size_t)B * 4);
  float* ev    = (float*)alloc((size_t)B * 4);
  int*   cl    = (int*)alloc((size_t)B * 4);
  int*   order = (int*)alloc((size_t)B * 4);
  int*      counts = (int*)alloc((size_t)C * 4);
  unsigned* smax   = (unsigned*)alloc((size_t)C * 4);
  float*    denom  = (float*)alloc((size_t)C * 4);
  int* starts = (int*)alloc((size_t)(C + 1) * 4);
  int* cursor = (int*)alloc((size_t)C * 4);
  (void)ws_size; (void)n_in; (void)out_size;

  size_t zlen = (size_t)((char*)denom - (char*)counts) + (size_t)C * 4;
  hipMemsetAsync(counts, 0, zlen, stream);
  hipMemsetAsync(score, 0, (size_t)B * 4, stream);

  cvt_f32_bf16_k<<<(B * 512 / 4 + 255) / 256, 256, 0, stream>>>(h, hbf, B * 512 / 4);
  cvt_f32_bf16_k<<<(C * 512 / 4 + 255) / 256, 256, 0, stream>>>(g, gbf, C * 512 / 4);
  const int n4w = 512 * 512 / 4;
  cvt3_f32_bf16_k<<<(3 * n4w + 255) / 256, 256, 0, stream>>>(Wk, Wq, W, Wk_bf, n4w);

  prep_cluster_k<<<(B + 255) / 256, 256, 0, stream>>>(vn, nid, cl, counts, B);
  prefix_k<<<1, 1024, 0, stream>>>(counts, starts, cursor, C);
  scatter_k<<<(B + 255) / 256, 256, 0, stream>>>(cl, cursor, order, B);

  // qb = g @ Wq^T + attn_bias
  gemm128_k<0><<<4 * ((C + 127) / 128), 256, 0, stream>>>(gbf, Wq_bf, C, ab, qb);

  // score[m] += per-256-col-block sum of tanh(h@Wk^T + qb[cl])·Ws
  // (bs dropped: softmax invariant to constant shift)
  gemm256sq_score_k<<<2 * ((B + 255) / 256), 1024, 0, stream>>>(
      hbf, Wk_bf, B, qb, cl, Ws, score);

  seg_max_k<<<(B + 255) / 256, 256, 0, stream>>>(score, cl, smax, B);
  seg_expsum_k<<<(B + 255) / 256, 256, 0, stream>>>(score, cl, smax, ev, denom, B);
  ctx_k<<<C, 256, 0, stream>>>(hbf, ev, order, starts, denom, ctx);

  cvt_f32_bf16_k<<<(C * 512 / 4 + 255) / 256, 256, 0, stream>>>(ctx, ctxbf, C * 512 / 4);

  // out = tanh(ctx @ W^T + b)
  gemm128_k<2><<<4 * ((C + 127) / 128), 256, 0, stream>>>(ctxbf, W_bf, C, b, (float*)d_out);
}